// Round 8
// baseline (110.328 us; speedup 1.0000x reference)
//
#include <hip/hip_runtime.h>
#include <math.h>

// Problem constants (reference: K=256, Q=64, T=500001 -> n = 500000)
#define K_ 256
#define Q_ 64
#define NT 500000
#define NTILES (NT / 16)                   // 31250 t-tiles of 16
#define TT_ 32                             // t-tiles per k_main block
#define GRID_MAIN ((NTILES + TT_ - 1) / TT_)   // 977
#define NSUM 245                           // k_sum blocks (256 thr x 8 elem)

// Workspace layout (float offsets). No fp32 u2 array (epilogue recomputes
// u2 from r) — only the two bf16 parity copies.
#define WS_BETA0  2
#define WS_U2B0   4
#define U2ELEMS   (Q_ + NT + 16)               // 500080 ushorts
#define U2F       ((U2ELEMS + 1) / 2)          // 250040 floats
#define WS_U2B1   (WS_U2B0 + U2F)              // 250044
#define WS_BPACK  (WS_U2B1 + U2F)              // 500084 (8192 floats)
#define WS_W0     (WS_BPACK + 8192)            // 508276
#define WS_BETA   (WS_W0 + K_)                 // 508532
#define WS_PART   (WS_BETA + K_)               // 508788 (512)
#define WS_PART2  (WS_PART + 512)              // 509300 (512)
#define WS_OUT    (WS_PART2 + 512)             // 509812 (1024)
#define WS_CNT    (WS_OUT + 1024)              // 510836 (uint ticket)

typedef __attribute__((ext_vector_type(8))) __bf16 bf16x8;
typedef __attribute__((ext_vector_type(4))) float  f32x4;

__device__ __forceinline__ float softplusf(float x) {
    return (x > 20.f) ? x : log1pf(__expf(x));
}

__device__ __forceinline__ unsigned short f2bf(float f) {
    unsigned int u = __float_as_uint(f);
    u = u + 0x7FFFu + ((u >> 16) & 1u);   // RNE (positive normals here)
    return (unsigned short)(u >> 16);
}

// Kernel A: 8 elems/thread vectorized. Computes u2 on the fly, stores the
// two bf16 parity copies, reduces sum/sumsq to per-block partials
// (no atomics — R3 lesson).
__global__ void k_sum(const float* __restrict__ r,
                      const float* __restrict__ a0p,
                      const float* __restrict__ a1p,
                      float* __restrict__ ws) {
    __shared__ float red[8];
    int i0 = (blockIdx.x * 256 + threadIdx.x) * 8;
    float a0 = a0p[0], a1 = a1p[0];
    float v = 0.f, v2 = 0.f;
    if (i0 < NT) {                        // NT % 8 == 0: all-or-nothing
        float rr[9];
        *(float4*)&rr[0] = *(const float4*)(r + i0);
        *(float4*)&rr[4] = *(const float4*)(r + i0 + 4);
        rr[8] = r[i0 + 8];                // i0+8 <= NT, r has NT+1 entries
        unsigned short bs[8];
        #pragma unroll
        for (int j = 0; j < 8; ++j) {
            float u  = rr[j + 1] - a0 - a1 * rr[j];
            float u2 = u * u;
            bs[j] = f2bf(u2);
            v += u2;
            v2 = fmaf(u2, u2, v2);
        }
        unsigned short* b0 = (unsigned short*)(ws + WS_U2B0);
        unsigned short* b1 = (unsigned short*)(ws + WS_U2B1);
        __builtin_memcpy(b0 + Q_ + i0, bs, 16);          // 16B aligned
        b1[Q_ - 1 + i0] = bs[0];                         // b1[e] = u2_full[e+1]
        __builtin_memcpy(b1 + Q_ + i0, bs + 1, 12);      // dwordx3, aligned
        b1[Q_ + i0 + 6] = bs[7];
    }
    #pragma unroll
    for (int off = 32; off > 0; off >>= 1) {
        v  += __shfl_down(v,  off, 64);
        v2 += __shfl_down(v2, off, 64);
    }
    int wv = threadIdx.x >> 6;
    if ((threadIdx.x & 63) == 0) { red[wv * 2] = v; red[wv * 2 + 1] = v2; }
    __syncthreads();
    if (threadIdx.x == 0) {
        ws[WS_PART  + blockIdx.x] = red[0] + red[2] + red[4] + red[6];
        ws[WS_PART2 + blockIdx.x] = red[1] + red[3] + red[5] + red[7];
    }
}

// Kernel B: pack W fragments (bf16), softplus w0/beta, var-init bf16 seeds,
// beta0. Wpack (A/B-symmetric MFMA operand order):
//   Wpack[((kc*2+s)*64 + l)*8 + jj] = W'[32s + 8*(l>>4) + jj][kc*16 + (l&15)]
// where W'[j][kout] = softplus(raw_w[kout][63-j]).
__global__ void k_prep(const float* __restrict__ raw_beta0,
                       const float* __restrict__ raw_beta,
                       const float* __restrict__ raw_w0,
                       const float* __restrict__ raw_w,
                       float* __restrict__ ws) {
    int idx = blockIdx.x * blockDim.x + threadIdx.x;
    if (idx < 16384) {
        int jj = idx & 7, l = (idx >> 3) & 63, s = (idx >> 9) & 1, kc = idx >> 10;
        int j    = 32 * s + 8 * (l >> 4) + jj;
        int kout = kc * 16 + (l & 15);
        ((unsigned short*)(ws + WS_BPACK))[idx] =
            f2bf(softplusf(raw_w[kout * Q_ + (Q_ - 1 - j)]));
    } else if (idx < 16384 + K_) {
        int k = idx - 16384;
        ws[WS_W0 + k] = softplusf(raw_w0[k]);
    } else if (idx < 16384 + 2 * K_) {
        int k = idx - (16384 + K_);
        ws[WS_BETA + k] = softplusf(raw_beta[k]);
    } else if (idx < 16384 + 2 * K_ + Q_) {
        int j = idx - (16384 + 2 * K_);   // 0..63 == lane id (aligned wave)
        float s1 = 0.f, s2 = 0.f;
        #pragma unroll
        for (int p = j; p < NSUM; p += 64) {
            s1 += ws[WS_PART  + p];
            s2 += ws[WS_PART2 + p];
        }
        #pragma unroll
        for (int mask = 1; mask < 64; mask <<= 1) {
            s1 += __shfl_xor(s1, mask, 64);
            s2 += __shfl_xor(s2, mask, 64);
        }
        float n  = (float)NT;
        float var = (s2 - s1 * s1 / n) / (n - 1.f);
        unsigned short b = f2bf(var);
        ((unsigned short*)(ws + WS_U2B0))[j] = b;
        if (j < Q_ - 1) ((unsigned short*)(ws + WS_U2B1))[j] = b;
        if (j == 0) ws[WS_BETA0] = softplusf(raw_beta0[0]);
    }
}

// Kernel C: bf16 MFMA sliding-window GEMM + fused NLL, 32 tiles/block.
// W is the A-operand (C/D rows = kout, cols = t): k-reduction is within-lane.
// R7 forensics: VGPR_Count=60 proved the compiler was targeting 8 waves/EU
// (64-VGPR budget) and SANK the loop-invariant Wf/w0c/betc loads into the
// tile loop -> every tile serialized on ~16 global-load latencies (42 us,
// all pipes <27%). amdgpu_waves_per_eu(4,4) pins the budget at 128 VGPRs so
// the ~110-reg resident set stays in registers and loads hoist out.
__global__ void
__attribute__((amdgpu_waves_per_eu(4, 4)))
__launch_bounds__(256)
k_main(const float* __restrict__ r,
       const float* __restrict__ a0p,
       const float* __restrict__ a1p,
       float* __restrict__ ws, float* __restrict__ out) {
    __shared__ __align__(16) float sig[TT_ * 256];   // 32 KB
    __shared__ float red[4];
    __shared__ int lastflag;

    int tid = threadIdx.x;
    int l = tid & 63, w = tid >> 6;
    int m = l & 15, q = l >> 4;

    const unsigned short* bp = (const unsigned short*)(ws + WS_BPACK);
    float beta0v = ws[WS_BETA0];
    float a0 = a0p[0], a1 = a1p[0];

    // Preload W fragments (A-operand) + per-lane w0/beta float4s.
    bf16x8 Wf[4][2];
    f32x4 w0c[4], betc[4];
    #pragma unroll
    for (int i = 0; i < 4; ++i) {
        int kc = w * 4 + i;
        #pragma unroll
        for (int s = 0; s < 2; ++s)
            __builtin_memcpy(&Wf[i][s], bp + ((kc * 2 + s) * 64 + l) * 8, 16);
        w0c[i]  = *(const f32x4*)(ws + WS_W0   + kc * 16 + q * 4);
        betc[i] = *(const f32x4*)(ws + WS_BETA + kc * 16 + q * 4);
    }

    // u2 B-fragment: lane needs u2full[s0..s0+7], s0 = t0 + m + 8q (+32).
    // parity(s0)=m&1: even -> u2b0[s0], odd -> u2b1[s0-1] (4B-aligned loads).
    int par = m & 1;
    const char* abase = (const char*)(ws + (par ? WS_U2B1 : WS_U2B0));
    int aoff = (blockIdx.x * 512 + m + 8 * q - par) * 2;   // bytes

    bf16x8 U0, U1, U0n, U1n;
    __builtin_memcpy(&U0, abase + aoff, 16);
    __builtin_memcpy(&U1, abase + aoff + 64, 16);

    // Last block's over-reads (incl. prefetch overshoot) stay inside ws;
    // garbage tiles are masked in the epilogue (t >= NT).
    #pragma unroll 2
    for (int it = 0; it < TT_; ++it) {
        int anext = aoff + 32;
        __builtin_memcpy(&U0n, abase + anext, 16);
        __builtin_memcpy(&U1n, abase + anext + 64, 16);

        float p[4];
        #pragma unroll
        for (int i = 0; i < 4; ++i) {
            f32x4 acc = __builtin_amdgcn_mfma_f32_16x16x32_bf16(Wf[i][0], U0, w0c[i], 0, 0, 0);
            acc = __builtin_amdgcn_mfma_f32_16x16x32_bf16(Wf[i][1], U1, acc, 0, 0, 0);
            float pi;
            pi = betc[i][0] * fmaxf(acc[0], 0.f);
            pi = fmaf(betc[i][1], fmaxf(acc[1], 0.f), pi);
            pi = fmaf(betc[i][2], fmaxf(acc[2], 0.f), pi);
            pi = fmaf(betc[i][3], fmaxf(acc[3], 0.f), pi);
            p[i] = pi;
        }
        sig[it * 256 + tid] = (p[0] + p[1]) + (p[2] + p[3]);

        aoff = anext; U0 = U0n; U1 = U1n;
    }

    __syncthreads();   // the ONLY barrier before the epilogue

    // Epilogue: 512 t's per block, 2 per thread; u2 recomputed from r.
    float val = 0.f;
    #pragma unroll
    for (int rep = 0; rep < 2; ++rep) {
        int lt = tid + rep * 256;
        int tile = lt >> 4, tt = lt & 15;
        const float* sp = &sig[tile * 256 + tt];
        float s = 0.f;
        #pragma unroll
        for (int wq = 0; wq < 16; ++wq) s += sp[wq * 16];
        float sg = beta0v + s + 1e-8f;
        int t = blockIdx.x * 512 + lt;
        if (t < NT) {
            float u  = r[t + 1] - a0 - a1 * r[t];
            val += __logf(sg) + (u * u) / sg;
        }
    }
    #pragma unroll
    for (int mask = 1; mask < 64; mask <<= 1)
        val += __shfl_xor(val, mask, 64);
    if (l == 0) red[w] = val;
    __syncthreads();

    // Per-block partial store + device-fence ticket; last block finalizes.
    if (tid == 0) {
        ws[WS_OUT + blockIdx.x] = red[0] + red[1] + red[2] + red[3];
        __threadfence();                                   // release
        unsigned old = atomicAdd((unsigned*)(ws + WS_CNT), 1u);
        lastflag = (old == GRID_MAIN - 1);
    }
    __syncthreads();
    if (lastflag) {
        __threadfence();                                   // acquire
        float s = 0.f;
        for (int p = tid; p < GRID_MAIN; p += 256) s += ws[WS_OUT + p];
        #pragma unroll
        for (int mask = 1; mask < 64; mask <<= 1)
            s += __shfl_xor(s, mask, 64);
        if (l == 0) red[w] = s;
        __syncthreads();
        if (tid == 0)
            out[0] = 0.5f * (float)NT * 1.8378770664093453f
                   + 0.5f * (red[0] + red[1] + red[2] + red[3]);
    }
}

extern "C" void kernel_launch(void* const* d_in, const int* in_sizes, int n_in,
                              void* d_out, int out_size, void* d_ws, size_t ws_size,
                              hipStream_t stream) {
    const float* r        = (const float*)d_in[0];
    const float* a0       = (const float*)d_in[1];
    const float* a1       = (const float*)d_in[2];
    const float* raw_b0   = (const float*)d_in[3];
    const float* raw_beta = (const float*)d_in[4];
    const float* raw_w0   = (const float*)d_in[5];
    const float* raw_w    = (const float*)d_in[6];
    float* out = (float*)d_out;
    float* ws  = (float*)d_ws;

    hipMemsetAsync(ws + WS_CNT, 0, 4, stream);   // zero the ticket counter

    k_sum<<<NSUM, 256, 0, stream>>>(r, a0, a1, ws);

    int prep_threads = 16384 + 2 * K_ + Q_;   // 16960
    k_prep<<<(prep_threads + 255) / 256, 256, 0, stream>>>(
        raw_b0, raw_beta, raw_w0, raw_w, ws);

    k_main<<<GRID_MAIN, 256, 0, stream>>>(r, a0, a1, ws, out);
}

// Round 9
// 106.385 us; speedup vs baseline: 1.0371x; 1.0371x over previous
//
#include <hip/hip_runtime.h>
#include <math.h>

// Problem constants (reference: K=256, Q=64, T=500001 -> n = 500000)
#define K_ 256
#define Q_ 64
#define NT 500000
#define NTILES (NT / 16)                   // 31250 t-tiles of 16
#define TT_ 32                             // t-tiles per k_main block
#define GRID_MAIN ((NTILES + TT_ - 1) / TT_)   // 977
#define NSUM 245                           // k_sum blocks (256 thr x 8 elem)

// Workspace layout (float offsets). No fp32 u2 array (epilogue recomputes
// u2 from r) — only the two bf16 parity copies.
#define WS_BETA0  2
#define WS_U2B0   4
#define U2ELEMS   (Q_ + NT + 16)               // 500080 ushorts
#define U2F       ((U2ELEMS + 1) / 2)          // 250040 floats
#define WS_U2B1   (WS_U2B0 + U2F)              // 250044
#define WS_BPACK  (WS_U2B1 + U2F)              // 500084 (8192 floats)
#define WS_W0     (WS_BPACK + 8192)            // 508276
#define WS_BETA   (WS_W0 + K_)                 // 508532
#define WS_PART   (WS_BETA + K_)               // 508788 (512)
#define WS_PART2  (WS_PART + 512)              // 509300 (512)
#define WS_OUT    (WS_PART2 + 512)             // 509812 (1024)
#define WS_CNT    (WS_OUT + 1024)              // 510836 (uint ticket)

typedef __attribute__((ext_vector_type(8))) __bf16 bf16x8;
typedef __attribute__((ext_vector_type(4))) float  f32x4;

__device__ __forceinline__ float softplusf(float x) {
    return (x > 20.f) ? x : log1pf(__expf(x));
}

__device__ __forceinline__ unsigned short f2bf(float f) {
    unsigned int u = __float_as_uint(f);
    u = u + 0x7FFFu + ((u >> 16) & 1u);   // RNE (positive normals here)
    return (unsigned short)(u >> 16);
}

// Kernel A: 8 elems/thread vectorized. Computes u2 on the fly, stores the
// two bf16 parity copies, reduces sum/sumsq to per-block partials
// (no atomics — R3 lesson).
__global__ void k_sum(const float* __restrict__ r,
                      const float* __restrict__ a0p,
                      const float* __restrict__ a1p,
                      float* __restrict__ ws) {
    __shared__ float red[8];
    int i0 = (blockIdx.x * 256 + threadIdx.x) * 8;
    float a0 = a0p[0], a1 = a1p[0];
    float v = 0.f, v2 = 0.f;
    if (i0 < NT) {                        // NT % 8 == 0: all-or-nothing
        float rr[9];
        *(float4*)&rr[0] = *(const float4*)(r + i0);
        *(float4*)&rr[4] = *(const float4*)(r + i0 + 4);
        rr[8] = r[i0 + 8];                // i0+8 <= NT, r has NT+1 entries
        unsigned short bs[8];
        #pragma unroll
        for (int j = 0; j < 8; ++j) {
            float u  = rr[j + 1] - a0 - a1 * rr[j];
            float u2 = u * u;
            bs[j] = f2bf(u2);
            v += u2;
            v2 = fmaf(u2, u2, v2);
        }
        unsigned short* b0 = (unsigned short*)(ws + WS_U2B0);
        unsigned short* b1 = (unsigned short*)(ws + WS_U2B1);
        __builtin_memcpy(b0 + Q_ + i0, bs, 16);          // 16B aligned
        b1[Q_ - 1 + i0] = bs[0];                         // b1[e] = u2_full[e+1]
        __builtin_memcpy(b1 + Q_ + i0, bs + 1, 12);      // dwordx3, aligned
        b1[Q_ + i0 + 6] = bs[7];
    }
    #pragma unroll
    for (int off = 32; off > 0; off >>= 1) {
        v  += __shfl_down(v,  off, 64);
        v2 += __shfl_down(v2, off, 64);
    }
    int wv = threadIdx.x >> 6;
    if ((threadIdx.x & 63) == 0) { red[wv * 2] = v; red[wv * 2 + 1] = v2; }
    __syncthreads();
    if (threadIdx.x == 0) {
        ws[WS_PART  + blockIdx.x] = red[0] + red[2] + red[4] + red[6];
        ws[WS_PART2 + blockIdx.x] = red[1] + red[3] + red[5] + red[7];
    }
}

// Kernel B: pack W fragments (bf16), softplus w0/beta, var-init bf16 seeds,
// beta0. Wpack (A/B-symmetric MFMA operand order):
//   Wpack[((kc*2+s)*64 + l)*8 + jj] = W'[32s + 8*(l>>4) + jj][kc*16 + (l&15)]
// where W'[j][kout] = softplus(raw_w[kout][63-j]).
__global__ void k_prep(const float* __restrict__ raw_beta0,
                       const float* __restrict__ raw_beta,
                       const float* __restrict__ raw_w0,
                       const float* __restrict__ raw_w,
                       float* __restrict__ ws) {
    int idx = blockIdx.x * blockDim.x + threadIdx.x;
    if (idx < 16384) {
        int jj = idx & 7, l = (idx >> 3) & 63, s = (idx >> 9) & 1, kc = idx >> 10;
        int j    = 32 * s + 8 * (l >> 4) + jj;
        int kout = kc * 16 + (l & 15);
        ((unsigned short*)(ws + WS_BPACK))[idx] =
            f2bf(softplusf(raw_w[kout * Q_ + (Q_ - 1 - j)]));
    } else if (idx < 16384 + K_) {
        int k = idx - 16384;
        ws[WS_W0 + k] = softplusf(raw_w0[k]);
    } else if (idx < 16384 + 2 * K_) {
        int k = idx - (16384 + K_);
        ws[WS_BETA + k] = softplusf(raw_beta[k]);
    } else if (idx < 16384 + 2 * K_ + Q_) {
        int j = idx - (16384 + 2 * K_);   // 0..63 == lane id (aligned wave)
        float s1 = 0.f, s2 = 0.f;
        #pragma unroll
        for (int p = j; p < NSUM; p += 64) {
            s1 += ws[WS_PART  + p];
            s2 += ws[WS_PART2 + p];
        }
        #pragma unroll
        for (int mask = 1; mask < 64; mask <<= 1) {
            s1 += __shfl_xor(s1, mask, 64);
            s2 += __shfl_xor(s2, mask, 64);
        }
        float n  = (float)NT;
        float var = (s2 - s1 * s1 / n) / (n - 1.f);
        unsigned short b = f2bf(var);
        ((unsigned short*)(ws + WS_U2B0))[j] = b;
        if (j < Q_ - 1) ((unsigned short*)(ws + WS_U2B1))[j] = b;
        if (j == 0) ws[WS_BETA0] = softplusf(raw_beta0[0]);
    }
}

// Kernel C: bf16 MFMA sliding-window GEMM + fused NLL, 32 tiles/block.
// W is the A-operand (C/D rows = kout, cols = t): k-reduction is within-lane.
//
// R8 forensics: __launch_bounds__(256) clobbered amdgpu_waves_per_eu(4,4)
// (VGPR stayed 60; allocator kept targeting 8 waves/EU and sank the
// loop-invariant Wf/w0c/betc loads into the loop). Fix: NO __launch_bounds__,
// only flat_work_group_size + waves_per_eu(4,4) -> 128-VGPR budget.
//
// U-FIFO: U1(it) == U0(it+2) (s0 advances 16 elems/tile), so one 16B load
// per tile feeds both MFMA slices two tiles apart: F0..F3 = X(it..it+3),
// tile uses U0=F0, U1=F2; loads run 4 tiles ahead (~360 cyc of compute
// covers L2 latency). Halves vmem traffic vs R8.
__global__ void
__attribute__((amdgpu_flat_work_group_size(256, 256)))
__attribute__((amdgpu_waves_per_eu(4, 4)))
k_main(const float* __restrict__ r,
       const float* __restrict__ a0p,
       const float* __restrict__ a1p,
       float* __restrict__ ws, float* __restrict__ out) {
    __shared__ __align__(16) float sig[TT_ * 256];   // 32 KB
    __shared__ float red[4];
    __shared__ int lastflag;

    int tid = threadIdx.x;
    int l = tid & 63, w = tid >> 6;
    int m = l & 15, q = l >> 4;

    const unsigned short* bp = (const unsigned short*)(ws + WS_BPACK);
    float beta0v = ws[WS_BETA0];
    float a0 = a0p[0], a1 = a1p[0];

    // Preload W fragments (A-operand) + per-lane w0/beta float4s.
    bf16x8 Wf[4][2];
    f32x4 w0c[4], betc[4];
    #pragma unroll
    for (int i = 0; i < 4; ++i) {
        int kc = w * 4 + i;
        #pragma unroll
        for (int s = 0; s < 2; ++s)
            __builtin_memcpy(&Wf[i][s], bp + ((kc * 2 + s) * 64 + l) * 8, 16);
        w0c[i]  = *(const f32x4*)(ws + WS_W0   + kc * 16 + q * 4);
        betc[i] = *(const f32x4*)(ws + WS_BETA + kc * 16 + q * 4);
    }

    // u2 B-fragment: lane needs X(n) = u2full[b + 16n .. +7], b = t0+m+8q.
    // parity(b)=m&1: even -> u2b0, odd -> u2b1 shifted (4B-aligned loads).
    int par = m & 1;
    const char* abase = (const char*)(ws + (par ? WS_U2B1 : WS_U2B0));
    int aoff = (blockIdx.x * 512 + m + 8 * q - par) * 2;   // bytes; X(n) at +32n

    bf16x8 F0, F1, F2, F3;
    __builtin_memcpy(&F0, abase + aoff,      16);
    __builtin_memcpy(&F1, abase + aoff + 32, 16);
    __builtin_memcpy(&F2, abase + aoff + 64, 16);
    __builtin_memcpy(&F3, abase + aoff + 96, 16);

    // Last block's over-reads (incl. 4-deep prefetch overshoot, < 1 KB past
    // the u2 arrays) stay inside ws; garbage tiles masked in the epilogue.
    #define TILE_BODY(U0v, U1v, LD, nofs)                                     \
        {                                                                     \
            bf16x8 Ld_;                                                       \
            __builtin_memcpy(&Ld_, abase + aoff + (nofs), 16);                \
            float p[4];                                                       \
            _Pragma("unroll")                                                 \
            for (int i = 0; i < 4; ++i) {                                     \
                f32x4 acc = __builtin_amdgcn_mfma_f32_16x16x32_bf16(          \
                    Wf[i][0], U0v, w0c[i], 0, 0, 0);                          \
                acc = __builtin_amdgcn_mfma_f32_16x16x32_bf16(                \
                    Wf[i][1], U1v, acc, 0, 0, 0);                             \
                float pi;                                                     \
                pi = betc[i][0] * fmaxf(acc[0], 0.f);                         \
                pi = fmaf(betc[i][1], fmaxf(acc[1], 0.f), pi);                \
                pi = fmaf(betc[i][2], fmaxf(acc[2], 0.f), pi);                \
                pi = fmaf(betc[i][3], fmaxf(acc[3], 0.f), pi);                \
                p[i] = pi;                                                    \
            }                                                                 \
            sig[it * 256 + tid] = (p[0] + p[1]) + (p[2] + p[3]);              \
            LD = Ld_;                                                         \
        }

    #pragma unroll 1
    for (int it4 = 0; it4 < TT_ / 4; ++it4) {
        bf16x8 L0, L1, L2, L3;
        int it;
        it = it4 * 4;     TILE_BODY(F0, F2, L0, 128)
        it = it4 * 4 + 1; TILE_BODY(F1, F3, L1, 160)
        it = it4 * 4 + 2; TILE_BODY(F2, L0, L2, 192)
        it = it4 * 4 + 3; TILE_BODY(F3, L1, L3, 224)
        F0 = L0; F1 = L1; F2 = L2; F3 = L3;
        aoff += 128;
    }
    #undef TILE_BODY

    __syncthreads();   // the ONLY barrier before the epilogue

    // Epilogue: 512 t's per block, 2 per thread; u2 recomputed from r.
    float val = 0.f;
    #pragma unroll
    for (int rep = 0; rep < 2; ++rep) {
        int lt = tid + rep * 256;
        int tile = lt >> 4, tt = lt & 15;
        const float* sp = &sig[tile * 256 + tt];
        float s = 0.f;
        #pragma unroll
        for (int wq = 0; wq < 16; ++wq) s += sp[wq * 16];
        float sg = beta0v + s + 1e-8f;
        int t = blockIdx.x * 512 + lt;
        if (t < NT) {
            float u  = r[t + 1] - a0 - a1 * r[t];
            val += __logf(sg) + (u * u) / sg;
        }
    }
    #pragma unroll
    for (int mask = 1; mask < 64; mask <<= 1)
        val += __shfl_xor(val, mask, 64);
    if (l == 0) red[w] = val;
    __syncthreads();

    // Per-block partial store + device-fence ticket; last block finalizes.
    if (tid == 0) {
        ws[WS_OUT + blockIdx.x] = red[0] + red[1] + red[2] + red[3];
        __threadfence();                                   // release
        unsigned old = atomicAdd((unsigned*)(ws + WS_CNT), 1u);
        lastflag = (old == GRID_MAIN - 1);
    }
    __syncthreads();
    if (lastflag) {
        __threadfence();                                   // acquire
        float s = 0.f;
        for (int p = tid; p < GRID_MAIN; p += 256) s += ws[WS_OUT + p];
        #pragma unroll
        for (int mask = 1; mask < 64; mask <<= 1)
            s += __shfl_xor(s, mask, 64);
        if (l == 0) red[w] = s;
        __syncthreads();
        if (tid == 0)
            out[0] = 0.5f * (float)NT * 1.8378770664093453f
                   + 0.5f * (red[0] + red[1] + red[2] + red[3]);
    }
}

extern "C" void kernel_launch(void* const* d_in, const int* in_sizes, int n_in,
                              void* d_out, int out_size, void* d_ws, size_t ws_size,
                              hipStream_t stream) {
    const float* r        = (const float*)d_in[0];
    const float* a0       = (const float*)d_in[1];
    const float* a1       = (const float*)d_in[2];
    const float* raw_b0   = (const float*)d_in[3];
    const float* raw_beta = (const float*)d_in[4];
    const float* raw_w0   = (const float*)d_in[5];
    const float* raw_w    = (const float*)d_in[6];
    float* out = (float*)d_out;
    float* ws  = (float*)d_ws;

    hipMemsetAsync(ws + WS_CNT, 0, 4, stream);   // zero the ticket counter

    k_sum<<<NSUM, 256, 0, stream>>>(r, a0, a1, ws);

    int prep_threads = 16384 + 2 * K_ + Q_;   // 16960
    k_prep<<<(prep_threads + 255) / 256, 256, 0, stream>>>(
        raw_b0, raw_beta, raw_w0, raw_w, ws);

    k_main<<<GRID_MAIN, 256, 0, stream>>>(r, a0, a1, ws, out);
}